// Round 3
// baseline (240.482 us; speedup 1.0000x reference)
//
#include <hip/hip_runtime.h>

// PathWAEOld: embedding-gather + sum, WAE matvec+relu, leaky_relu, max-pool
// over paths, 4-class linear head + softmax + CE loss.
// Inputs fp32 (confirmed: bf16-reads gave NaN, fp32-reads finite).
// Output fp32 (harness: reference output float32 -> float*).

#define NPATH 16384
#define PLEN  50
#define RANDD 100
#define VDIMD 100
#define WAED  50
#define NCLS  4
#define HD    150   // RANDD + WAED
#define NBLK  1024  // 4096 waves -> 4 paths/wave

// order-preserving float->uint map for atomicMax on floats
__device__ __forceinline__ unsigned f2o(float f) {
    unsigned u = __float_as_uint(f);
    return (u & 0x80000000u) ? ~u : (u | 0x80000000u);
}
__device__ __forceinline__ float o2f(unsigned u) {
    return (u & 0x80000000u) ? __uint_as_float(u & 0x7FFFFFFFu)
                             : __uint_as_float(~u);
}

__global__ void __launch_bounds__(256)
pathwae_main(const int* __restrict__ x,
             const float* __restrict__ E_td,
             const float* __restrict__ E_wae,
             const float* __restrict__ W_enc,
             const float* __restrict__ b_enc,
             unsigned int* __restrict__ gmax)
{
    __shared__ float sh_W[VDIMD * WAED];   // 20 KB fp32 W_enc
    __shared__ float sh_bow[4][VDIMD];     // per-wave bag-of-words
    __shared__ float sh_wmax[4][HD];       // per-wave running max

    const int tid  = threadIdx.x;
    const int lane = tid & 63;
    const int warp = tid >> 6;

    for (int i = tid; i < VDIMD * WAED; i += 256) sh_W[i] = W_enc[i];
    __syncthreads();

    const int gwave = blockIdx.x * 4 + warp;   // 0..4095
    const int nwave = NBLK * 4;

    const bool is_td  = (lane < 25);
    const bool active = (lane < 50);
    const int  chunk  = is_td ? lane : (lane - 25);   // float4 chunk 0..24
    const float* tab  = is_td ? E_td : E_wae;

    float4 maxtd = make_float4(-3.4e38f, -3.4e38f, -3.4e38f, -3.4e38f);
    float  maxwae = -3.4e38f;
    const float benc = (lane < WAED) ? b_enc[lane] : 0.0f;

    for (int p = gwave; p < NPATH; p += nwave) {
        int mytok = (lane < PLEN) ? x[p * PLEN + lane] : 0;
        float ax = 0.f, ay = 0.f, az = 0.f, aw = 0.f;
        #pragma unroll 10
        for (int l = 0; l < PLEN; ++l) {
            int tok = __shfl(mytok, l);
            if (active) {
                // row start = tok*100 floats = 400B; chunk*16B -> 16B aligned
                float4 v = *(const float4*)(tab + tok * 100 + chunk * 4);
                ax += v.x; ay += v.y; az += v.z; aw += v.w;
            }
        }
        // stage bow (lanes 25..49) into per-wave LDS; same-wave DS ops are
        // processed in program order -> no barrier needed.
        if (active && !is_td) {
            float* dst = &sh_bow[warp][chunk * 4];
            dst[0] = ax; dst[1] = ay; dst[2] = az; dst[3] = aw;
        }
        if (lane < WAED) {
            float w = benc;
            #pragma unroll 10
            for (int i = 0; i < VDIMD; ++i)
                w = fmaf(sh_bow[warp][i], sh_W[i * WAED + lane], w);
            w = fmaxf(w, 0.0f);               // relu; leaky of >=0 is identity
            maxwae = fmaxf(maxwae, w);
        }
        if (is_td) {                          // leaky_relu on path_random
            maxtd.x = fmaxf(maxtd.x, ax > 0.f ? ax : 0.01f * ax);
            maxtd.y = fmaxf(maxtd.y, ay > 0.f ? ay : 0.01f * ay);
            maxtd.z = fmaxf(maxtd.z, az > 0.f ? az : 0.01f * az);
            maxtd.w = fmaxf(maxtd.w, aw > 0.f ? aw : 0.01f * aw);
        }
    }

    if (is_td) {
        sh_wmax[warp][chunk * 4 + 0] = maxtd.x;
        sh_wmax[warp][chunk * 4 + 1] = maxtd.y;
        sh_wmax[warp][chunk * 4 + 2] = maxtd.z;
        sh_wmax[warp][chunk * 4 + 3] = maxtd.w;
    }
    if (lane < WAED) sh_wmax[warp][RANDD + lane] = maxwae;
    __syncthreads();
    if (tid < HD) {
        float m = fmaxf(fmaxf(sh_wmax[0][tid], sh_wmax[1][tid]),
                        fmaxf(sh_wmax[2][tid], sh_wmax[3][tid]));
        atomicMax(&gmax[tid], f2o(m));        // device-scope, cross-XCD safe
    }
}

__global__ void __launch_bounds__(256)
pathwae_final(const unsigned int* __restrict__ gmax,
              const int* __restrict__ y,
              const float* __restrict__ w_out,
              const float* __restrict__ b_out,
              float* __restrict__ out)
{
    __shared__ float pm[HD];
    __shared__ float lg[NCLS];
    const int tid = threadIdx.x;
    if (tid < HD) pm[tid] = o2f(gmax[tid]);
    __syncthreads();
    if (tid < NCLS) {
        float s = b_out[tid];
        for (int d = 0; d < HD; ++d)
            s = fmaf(w_out[tid * HD + d], pm[d], s);
        lg[tid] = s;
    }
    __syncthreads();
    if (tid == 0) {
        int label = 0, best = y[0];
        for (int c = 1; c < NCLS; ++c)
            if (y[c] > best) { best = y[c]; label = c; }
        float m = lg[0];
        for (int c = 1; c < NCLS; ++c) m = fmaxf(m, lg[c]);
        float e[NCLS], s = 0.f;
        for (int c = 0; c < NCLS; ++c) { e[c] = expf(lg[c] - m); s += e[c]; }
        float prob[NCLS];
        for (int c = 0; c < NCLS; ++c) prob[c] = e[c] / s;
        // loss = -log_softmax(prob)[label]  (softmax-of-softmax, per ref)
        float m2 = prob[0];
        for (int c = 1; c < NCLS; ++c) m2 = fmaxf(m2, prob[c]);
        float s2 = 0.f;
        for (int c = 0; c < NCLS; ++c) s2 += expf(prob[c] - m2);
        float lse = m2 + logf(s2);
        for (int c = 0; c < NCLS; ++c) out[c] = prob[c];
        out[NCLS] = -(prob[label] - lse);
    }
}

extern "C" void kernel_launch(void* const* d_in, const int* in_sizes, int n_in,
                              void* d_out, int out_size, void* d_ws, size_t ws_size,
                              hipStream_t stream) {
    const int* x          = (const int*)d_in[0];
    const int* y          = (const int*)d_in[1];
    const float* E_td     = (const float*)d_in[2];
    const float* E_wae    = (const float*)d_in[3];
    const float* W_enc    = (const float*)d_in[4];
    const float* b_enc    = (const float*)d_in[5];
    const float* w_out    = (const float*)d_in[6];
    const float* b_out    = (const float*)d_in[7];
    float* out            = (float*)d_out;
    unsigned int* gmax    = (unsigned int*)d_ws;   // 150 ordered-uint maxes

    hipMemsetAsync(gmax, 0, HD * sizeof(unsigned int), stream);
    pathwae_main<<<NBLK, 256, 0, stream>>>(x, E_td, E_wae, W_enc, b_enc, gmax);
    pathwae_final<<<1, 256, 0, stream>>>(gmax, y, w_out, b_out, out);
}